// Round 10
// baseline (464.367 us; speedup 1.0000x reference)
//
#include <hip/hip_runtime.h>
#include <math.h>

// ---------------- problem constants ----------------
#define HH 120
#define WW 160
#define NPTS (HH * WW)            // 19200
#define FXC 572.4114f
#define FYC 573.57043f
#define CXC 325.2611f
#define CYC 242.04899f

// z-bucket grid (partition only -> correctness never depends on ZMIN/ZMAX)
#define NB 128
#define ZMIN 0.1f
#define ZMAX 2.1f
#define WB ((ZMAX - ZMIN) / NB)       // 0.015625
#define INVWB (NB / (ZMAX - ZMIN))    // 64.0

#define PAD 16                        // sentinel pad per cloud (overscan target)
#define CLOUD_STRIDE (NPTS + PAD)

#define NBLK 600                      // = 2*NPTS/64; one wave per block
#define MASK_WGT 1.3989422804014327f  // exp(0)*inv_sqrt_2pi + 1

typedef float __attribute__((ext_vector_type(4))) f4;

__device__ __forceinline__ void backproject_pt(int idx, float d,
                                               float& px, float& py, float& pz) {
    int y = idx / WW;
    int x = idx - y * WW;
    px = ((float)x - CXC) * d * (1.0f / FXC);
    py = ((float)y - CYC) * d * (1.0f / FYC);
    pz = d;
}

__device__ __forceinline__ float min3f(float a, float b, float c) {
    float d;
    asm("v_min3_f32 %0, %1, %2, %3" : "=v"(d) : "v"(a), "v"(b), "v"(c));
    return d;
}

__device__ __forceinline__ int zbucket(float z) {
    int b = (int)((z - ZMIN) * INVWB);
    return b < 0 ? 0 : (b > NB - 1 ? NB - 1 : b);
}

// grid barrier: release-fence, arrive, acquire-spin. All 600 one-wave blocks
// are co-resident (2.3 blocks/CU, 64 thr, ~110 VGPR, 0 LDS), so spinning is
// deadlock-free. Agent-scope atomics emit the L2 cache maintenance needed for
// cross-XCD visibility (same primitives as the validated last-block pattern).
__device__ __forceinline__ void gridbar(int* bar, int target) {
    __threadfence();
    if (threadIdx.x == 0) {
        __hip_atomic_fetch_add(bar, 1, __ATOMIC_ACQ_REL, __HIP_MEMORY_SCOPE_AGENT);
        while (__hip_atomic_load(bar, __ATOMIC_ACQUIRE, __HIP_MEMORY_SCOPE_AGENT) < target)
            __builtin_amdgcn_s_sleep(2);
    }
    __syncthreads();
    __threadfence();
}

__device__ __forceinline__ int wscan_incl(int v, int lane) {
#pragma unroll
    for (int off = 1; off < 64; off <<= 1) {
        int u = __shfl_up(v, off, 64);
        if (lane >= off) v += u;
    }
    return v;
}

// ---------------- the fused kernel ----------------
// ctrl region (zeroed by memset node before launch):
//   ints[0]         bar
//   ints[16..272)   cnt[2*NB]
//   ints[272..528)  cur[2*NB]
//   ints[528..786)  offs[2*(NB+1)]
//   floats[800..803) accf: cham_sum, pos_sum, neg_sum
//   ints[803..805)  acci: pos_cnt, neg_cnt
__global__ void __launch_bounds__(64) fused_k(const float* __restrict__ pred_PM,
                                              const float* __restrict__ pred_Ms,
                                              const float* __restrict__ depth_src,
                                              const float* __restrict__ depth_tgt,
                                              int* __restrict__ ctrl,
                                              f4* __restrict__ pts,
                                              f4* __restrict__ sorted,
                                              float* __restrict__ out) {
    const int lane = threadIdx.x;
    const int blk = blockIdx.x;
    const int gid = blk * 64 + lane;          // [0, 38400)

    int* bar   = ctrl;
    int* cnt   = ctrl + 16;
    int* cur   = ctrl + 272;
    int* offs  = ctrl + 528;
    float* accf = (float*)(ctrl + 800);
    int* acci  = ctrl + 803;

    // ---- P1: backproject + histogram (1 point per thread) ----
    {
        int dir = (gid >= NPTS);
        int idx = gid - dir * NPTS;
        float d = dir ? depth_tgt[idx] : depth_src[idx];
        float px, py, pz;
        backproject_pt(idx, d, px, py, pz);
        f4 v = {px, py, pz, fmaf(px, px, fmaf(py, py, pz * pz))};
        pts[gid] = v;
        atomicAdd(&cnt[dir * NB + zbucket(pz)], 1);
        if (blk == 0 && lane < 2 * PAD) {     // sentinel pads (used in P4)
            int c = lane >> 4, k = lane & (PAD - 1);
            f4 s = {0.0f, 0.0f, 0.0f, 1e30f};
            sorted[c * CLOUD_STRIDE + NPTS + k] = s;
        }
    }
    gridbar(bar, 1 * NBLK);

    // ---- P2: exclusive prefix scan (block 0, one wave, both clouds) ----
    if (blk == 0) {
#pragma unroll
        for (int c = 0; c < 2; ++c) {
            int v0 = cnt[c * NB + lane];
            int v1 = cnt[c * NB + 64 + lane];
            int s0 = wscan_incl(v0, lane);
            int T0 = __shfl(s0, 63, 64);
            int s1 = wscan_incl(v1, lane) + T0;
            int e0 = s0 - v0, e1 = s1 - v1;
            offs[c * (NB + 1) + lane] = e0;
            offs[c * (NB + 1) + 64 + lane] = e1;
            cur[c * NB + lane] = e0;
            cur[c * NB + 64 + lane] = e1;
            if (lane == 63) offs[c * (NB + 1) + NB] = s1;   // = NPTS
        }
    }
    gridbar(bar, 2 * NBLK);

    // ---- P3: scatter into z-bucketed order ----
    {
        int dir = (gid >= NPTS);
        f4 p = pts[gid];
        int b = zbucket(p.z);
        int pos = atomicAdd(&cur[dir * NB + b], 1);
        sorted[dir * CLOUD_STRIDE + pos] = p;
    }
    gridbar(bar, 3 * NBLK);

    // ---- P5: mask loss (first 300 blocks, 1 elem per thread) ----
    if (gid < NPTS) {
        float p = pred_PM[gid];
        p = fminf(fmaxf(p, 1e-7f), 1.0f - 1e-7f);
        float t = pred_Ms[gid];
        float ps = 0.0f, ns = 0.0f;
        int pc = 0, nc = 0;
        if (t > 0.0f)       { ps = -t * logf(p) * MASK_WGT; pc = 1; }
        else if (t == 0.0f) { ns = -logf(1.0f - p) * MASK_WGT; nc = 1; }
#pragma unroll
        for (int off = 32; off; off >>= 1) {
            ps += __shfl_xor(ps, off, 64);
            ns += __shfl_xor(ns, off, 64);
            pc += __shfl_xor(pc, off, 64);
            nc += __shfl_xor(nc, off, 64);
        }
        if (lane == 0) {
            atomicAdd(&accf[1], ps);
            atomicAdd(&accf[2], ns);
            atomicAdd(&acci[0], pc);
            atomicAdd(&acci[1], nc);
        }
    }

    // ---- P4: pruned chamfer (each wave owns 64 sorted queries) ----
    {
        int dir = (blk >= NBLK / 2);
        int grp = blk - dir * (NBLK / 2);
        const f4* SQ = sorted + dir * CLOUD_STRIDE;
        const f4* SB = sorted + (1 - dir) * CLOUD_STRIDE;
        const int* offB = offs + (1 - dir) * (NB + 1);

        f4 a = SQ[grp * 64 + lane];
        const float n2x = -2.0f * a.x, n2y = -2.0f * a.y, n2z = -2.0f * a.z;
        const float az = a.z, a2 = a.w;
        float mnA = INFINITY, mnB = INFINITY;

        int bl = zbucket(az), bh = bl;
#pragma unroll
        for (int off = 32; off; off >>= 1) {
            bl = min(bl, __shfl_xor(bl, off, 64));
            bh = max(bh, __shfl_xor(bh, off, 64));
        }

        auto scan16 = [&](int c0, int c1) {
            for (int j = c0; j < c1; j += 16) {
                f4 q[16];
#pragma unroll
                for (int k = 0; k < 16; ++k) q[k] = SB[j + k];
#pragma unroll
                for (int k = 0; k < 16; k += 4) {
                    float r0 = fmaf(n2x, q[k+0].x, fmaf(n2y, q[k+0].y, fmaf(n2z, q[k+0].z, q[k+0].w)));
                    float r1 = fmaf(n2x, q[k+1].x, fmaf(n2y, q[k+1].y, fmaf(n2z, q[k+1].z, q[k+1].w)));
                    float r2 = fmaf(n2x, q[k+2].x, fmaf(n2y, q[k+2].y, fmaf(n2z, q[k+2].z, q[k+2].w)));
                    float r3 = fmaf(n2x, q[k+3].x, fmaf(n2y, q[k+3].y, fmaf(n2z, q[k+3].z, q[k+3].w)));
                    mnA = min3f(mnA, r0, r1);
                    mnB = min3f(mnB, r2, r3);
                }
            }
        };

        scan16(offB[bl], offB[bh + 1]);

        int lo = bl, hi = bh;
        while (true) {
            float mn = fminf(mnA, mnB);
            float dcur = fmaxf(a2 + mn, 0.0f);
            float dl = az - (ZMIN + lo * WB);
            float dr = (ZMIN + (hi + 1) * WB) - az;
            bool needL = (dl * dl < dcur);
            bool needR = (dr * dr < dcur);
            bool anyL = (lo > 0) && __any(needL);
            bool anyR = (hi < NB - 1) && __any(needR);
            if (!anyL && !anyR) break;
            if (anyL) { --lo; scan16(offB[lo], offB[lo + 1]); }
            if (anyR) { ++hi; scan16(offB[hi], offB[hi + 1]); }
        }

        float w = fmaxf(a2 + fminf(mnA, mnB), 0.0f);
#pragma unroll
        for (int off = 32; off; off >>= 1) w += __shfl_xor(w, off, 64);
        if (lane == 0) atomicAdd(&accf[0], w);
    }
    gridbar(bar, 4 * NBLK);

    // ---- epilogue ----
    if (blk == 0 && lane == 0) {
        float cham = accf[0], pos = accf[1], neg = accf[2];
        int cp = acci[0], cn = acci[1];
        out[0] = cham * (1.0f / (float)NPTS);
        float loss = 0.0f;
        if (cp > 0) loss += pos / (float)cp;
        if (cn > 0) loss += neg / (float)cn;
        out[1] = loss;
    }
}

// ---------------- launcher ----------------
extern "C" void kernel_launch(void* const* d_in, const int* in_sizes, int n_in,
                              void* d_out, int out_size, void* d_ws, size_t ws_size,
                              hipStream_t stream) {
    const float* pred_PM   = (const float*)d_in[0];
    const float* pred_Ms   = (const float*)d_in[1];
    const float* depth_src = (const float*)d_in[2];
    const float* depth_tgt = (const float*)d_in[3];
    float* out = (float*)d_out;

    // workspace: [0,4096) ctrl (zeroed every call); then pts; then sorted
    int* ctrl  = (int*)d_ws;
    f4* pts    = (f4*)((char*)d_ws + 4096);           // 2*NPTS*16      = 614400 B
    f4* sorted = pts + 2 * NPTS;                      // 2*(NPTS+16)*16 = 614912 B

    hipMemsetAsync(ctrl, 0, 4096, stream);
    fused_k<<<NBLK, 64, 0, stream>>>(pred_PM, pred_Ms, depth_src, depth_tgt,
                                     ctrl, pts, sorted, out);
}

// Round 11
// 81.858 us; speedup vs baseline: 5.6728x; 5.6728x over previous
//
#include <hip/hip_runtime.h>
#include <math.h>

// ---------------- problem constants ----------------
#define HH 120
#define WW 160
#define NPTS (HH * WW)            // 19200
#define FXC 572.4114f
#define FYC 573.57043f
#define CXC 325.2611f
#define CYC 242.04899f

// z-bucket grid (partition only -> correctness never depends on ZMIN/ZMAX)
#define NB 128
#define ZMIN 0.1f
#define ZMAX 2.1f
#define WB ((ZMAX - ZMIN) / NB)       // 0.015625
#define INVWB (NB / (ZMAX - ZMIN))    // 64.0

#define PAD 16                        // sentinel pad per cloud (overscan target)
#define CLOUD_STRIDE (NPTS + PAD)

#define MASK_WGT 1.3989422804014327f  // exp(0)*inv_sqrt_2pi + 1

// chamfer kernel geometry: 150 blocks x 4 waves = 600 waves; wave w owns
// query group (w % 300) of direction (w / 300); first 300 waves also do mask.
#define CH_BLKS 150

typedef float __attribute__((ext_vector_type(4))) f4;

__device__ __forceinline__ void backproject_pt(int idx, float d,
                                               float& px, float& py, float& pz) {
    int y = idx / WW;
    int x = idx - y * WW;
    px = ((float)x - CXC) * d * (1.0f / FXC);
    py = ((float)y - CYC) * d * (1.0f / FYC);
    pz = d;
}

__device__ __forceinline__ float min3f(float a, float b, float c) {
    float d;
    asm("v_min3_f32 %0, %1, %2, %3" : "=v"(d) : "v"(a), "v"(b), "v"(c));
    return d;
}

__device__ __forceinline__ int zbucket(float z) {
    int b = (int)((z - ZMIN) * INVWB);
    return b < 0 ? 0 : (b > NB - 1 ? NB - 1 : b);
}

__device__ __forceinline__ int wscan_incl(int v, int lane) {
#pragma unroll
    for (int off = 1; off < 64; off <<= 1) {
        int u = __shfl_up(v, off, 64);
        if (lane >= off) v += u;
    }
    return v;
}

// ---------------- kernel 1: single-workgroup prep ----------------
// One 1024-thread block does: zero ctrl, sentinel pads, backproject+histogram
// (LDS counters), wave-scan (waves 0/1), scatter via LDS cursors. All phase
// separation is __syncthreads() -- no grid sync anywhere.
// ctrl: ints[0]=pos_cnt, [1]=neg_cnt, [2]=done; floats[4..7)=cham,pos,neg sums.
__global__ void __launch_bounds__(1024) prep_k(const float* __restrict__ depth_src,
                                               const float* __restrict__ depth_tgt,
                                               f4* __restrict__ sorted,
                                               int* __restrict__ offs_g,
                                               int* __restrict__ ctrl) {
    __shared__ int cnt[2 * NB];
    __shared__ int cur[2 * NB];
    const int tid = threadIdx.x;

    if (tid < 2 * NB) cnt[tid] = 0;
    if (tid < 8) ctrl[tid] = 0;                 // acci + accf (0 bits == 0.0f)
    if (tid < 2 * PAD) {                        // sentinels for scan16 overscan
        int c = tid >> 4, k = tid & (PAD - 1);
        f4 s = {0.0f, 0.0f, 0.0f, 1e30f};
        sorted[c * CLOUD_STRIDE + NPTS + k] = s;
    }
    __syncthreads();

    // P1: histogram (backproject recomputed in P3; cheaper than spilling)
    for (int i = tid; i < 2 * NPTS; i += 1024) {
        int dir = (i >= NPTS);
        int idx = i - dir * NPTS;
        float d = dir ? depth_tgt[idx] : depth_src[idx];
        float px, py, pz;
        backproject_pt(idx, d, px, py, pz);
        atomicAdd(&cnt[dir * NB + zbucket(pz)], 1);
    }
    __syncthreads();

    // P2: exclusive scan, wave c handles cloud c (validated in R10, absmax 0)
    if (tid < 128) {
        int c = tid >> 6, lane = tid & 63;
        int v0 = cnt[c * NB + lane];
        int v1 = cnt[c * NB + 64 + lane];
        int s0 = wscan_incl(v0, lane);
        int T0 = __shfl(s0, 63, 64);
        int s1 = wscan_incl(v1, lane) + T0;
        int e0 = s0 - v0, e1 = s1 - v1;
        cur[c * NB + lane] = e0;
        cur[c * NB + 64 + lane] = e1;
        offs_g[c * (NB + 1) + lane] = e0;
        offs_g[c * (NB + 1) + 64 + lane] = e1;
        if (lane == 63) offs_g[c * (NB + 1) + NB] = s1;   // = NPTS
    }
    __syncthreads();

    // P3: scatter into z-bucketed order
    for (int i = tid; i < 2 * NPTS; i += 1024) {
        int dir = (i >= NPTS);
        int idx = i - dir * NPTS;
        float d = dir ? depth_tgt[idx] : depth_src[idx];
        float px, py, pz;
        backproject_pt(idx, d, px, py, pz);
        f4 v = {px, py, pz, fmaf(px, px, fmaf(py, py, pz * pz))};
        int pos = atomicAdd(&cur[dir * NB + zbucket(pz)], 1);
        sorted[dir * CLOUD_STRIDE + pos] = v;
    }
}

// ---------------- kernel 2: pruned chamfer + mask loss + epilogue ----------------
__global__ void __launch_bounds__(256) chamfer_k(const f4* __restrict__ sorted,
                                                 const int* __restrict__ offs,
                                                 const float* __restrict__ pred_PM,
                                                 const float* __restrict__ pred_Ms,
                                                 int* __restrict__ ctrl,
                                                 float* __restrict__ out) {
    const int tid = threadIdx.x;
    const int lane = tid & 63;
    const int wv = blockIdx.x * 4 + (tid >> 6);   // 0..599
    int* acci = ctrl;
    float* accf = (float*)(ctrl + 4);

    // ---- mask loss: waves 0..299, 64 elements each ----
    if (wv < 300) {
        int i = wv * 64 + lane;
        float p = pred_PM[i];
        p = fminf(fmaxf(p, 1e-7f), 1.0f - 1e-7f);
        float t = pred_Ms[i];
        float ps = 0.0f, ns = 0.0f;
        int pc = 0, nc = 0;
        if (t > 0.0f)       { ps = -t * logf(p) * MASK_WGT; pc = 1; }
        else if (t == 0.0f) { ns = -logf(1.0f - p) * MASK_WGT; nc = 1; }
#pragma unroll
        for (int off = 32; off; off >>= 1) {
            ps += __shfl_xor(ps, off, 64);
            ns += __shfl_xor(ns, off, 64);
            pc += __shfl_xor(pc, off, 64);
            nc += __shfl_xor(nc, off, 64);
        }
        if (lane == 0) {
            atomicAdd(&accf[1], ps);
            atomicAdd(&accf[2], ns);
            atomicAdd(&acci[0], pc);
            atomicAdd(&acci[1], nc);
        }
    }

    // ---- pruned chamfer: wave wv owns query group (wv%300), dir (wv/300) ----
    {
        int dir = (wv >= 300);
        int grp = wv - dir * 300;
        const f4* SQ = sorted + dir * CLOUD_STRIDE;
        const f4* SB = sorted + (1 - dir) * CLOUD_STRIDE;
        const int* offB = offs + (1 - dir) * (NB + 1);

        f4 a = SQ[grp * 64 + lane];
        const float n2x = -2.0f * a.x, n2y = -2.0f * a.y, n2z = -2.0f * a.z;
        const float az = a.z, a2 = a.w;
        float mnA = INFINITY, mnB = INFINITY;

        int bl = zbucket(az), bh = bl;
#pragma unroll
        for (int off = 32; off; off >>= 1) {
            bl = min(bl, __shfl_xor(bl, off, 64));
            bh = max(bh, __shfl_xor(bh, off, 64));
        }

        auto scan16 = [&](int c0, int c1) {
            for (int j = c0; j < c1; j += 16) {
                f4 q[16];
#pragma unroll
                for (int k = 0; k < 16; ++k) q[k] = SB[j + k];
#pragma unroll
                for (int k = 0; k < 16; k += 4) {
                    float r0 = fmaf(n2x, q[k+0].x, fmaf(n2y, q[k+0].y, fmaf(n2z, q[k+0].z, q[k+0].w)));
                    float r1 = fmaf(n2x, q[k+1].x, fmaf(n2y, q[k+1].y, fmaf(n2z, q[k+1].z, q[k+1].w)));
                    float r2 = fmaf(n2x, q[k+2].x, fmaf(n2y, q[k+2].y, fmaf(n2z, q[k+2].z, q[k+2].w)));
                    float r3 = fmaf(n2x, q[k+3].x, fmaf(n2y, q[k+3].y, fmaf(n2z, q[k+3].z, q[k+3].w)));
                    mnA = min3f(mnA, r0, r1);
                    mnB = min3f(mnB, r2, r3);
                }
            }
        };

        scan16(offB[bl], offB[bh + 1]);

        int lo = bl, hi = bh;
        while (true) {
            float mn = fminf(mnA, mnB);
            float dcur = fmaxf(a2 + mn, 0.0f);
            float dl = az - (ZMIN + lo * WB);
            float dr = (ZMIN + (hi + 1) * WB) - az;
            bool needL = (dl * dl < dcur);
            bool needR = (dr * dr < dcur);
            bool anyL = (lo > 0) && __any(needL);
            bool anyR = (hi < NB - 1) && __any(needR);
            if (!anyL && !anyR) break;
            if (anyL) { --lo; scan16(offB[lo], offB[lo + 1]); }
            if (anyR) { ++hi; scan16(offB[hi], offB[hi + 1]); }
        }

        float w = fmaxf(a2 + fminf(mnA, mnB), 0.0f);
#pragma unroll
        for (int off = 32; off; off >>= 1) w += __shfl_xor(w, off, 64);
        if (lane == 0) atomicAdd(&accf[0], w);
    }

    // ---- last-finished-block epilogue (validated done-counter pattern) ----
    __syncthreads();
    if (tid == 0) {
        __threadfence();
        int old = __hip_atomic_fetch_add(&acci[2], 1, __ATOMIC_ACQ_REL,
                                         __HIP_MEMORY_SCOPE_AGENT);
        if (old == CH_BLKS - 1) {
            __threadfence();
            float cham = __hip_atomic_load(&accf[0], __ATOMIC_RELAXED, __HIP_MEMORY_SCOPE_AGENT);
            float pos  = __hip_atomic_load(&accf[1], __ATOMIC_RELAXED, __HIP_MEMORY_SCOPE_AGENT);
            float neg  = __hip_atomic_load(&accf[2], __ATOMIC_RELAXED, __HIP_MEMORY_SCOPE_AGENT);
            int cp = __hip_atomic_load(&acci[0], __ATOMIC_RELAXED, __HIP_MEMORY_SCOPE_AGENT);
            int cn = __hip_atomic_load(&acci[1], __ATOMIC_RELAXED, __HIP_MEMORY_SCOPE_AGENT);
            out[0] = cham * (1.0f / (float)NPTS);
            float loss = 0.0f;
            if (cp > 0) loss += pos / (float)cp;
            if (cn > 0) loss += neg / (float)cn;
            out[1] = loss;
        }
    }
}

// ---------------- launcher ----------------
extern "C" void kernel_launch(void* const* d_in, const int* in_sizes, int n_in,
                              void* d_out, int out_size, void* d_ws, size_t ws_size,
                              hipStream_t stream) {
    const float* pred_PM   = (const float*)d_in[0];
    const float* pred_Ms   = (const float*)d_in[1];
    const float* depth_src = (const float*)d_in[2];
    const float* depth_tgt = (const float*)d_in[3];
    float* out = (float*)d_out;

    // workspace: ctrl[16 ints] | offs[2*(NB+1)] | (align 16) sorted
    int* ctrl  = (int*)d_ws;
    int* offs  = ctrl + 16;                              // 258 ints
    f4* sorted = (f4*)((char*)d_ws + 2048);              // 2*(NPTS+PAD)*16 B

    prep_k<<<1, 1024, 0, stream>>>(depth_src, depth_tgt, sorted, offs, ctrl);
    chamfer_k<<<CH_BLKS, 256, 0, stream>>>(sorted, offs, pred_PM, pred_Ms,
                                           ctrl, out);
}

// Round 12
// 77.731 us; speedup vs baseline: 5.9740x; 1.0531x over previous
//
#include <hip/hip_runtime.h>
#include <math.h>

// ---------------- problem constants ----------------
#define HH 120
#define WW 160
#define NPTS (HH * WW)            // 19200
#define FXC 572.4114f
#define FYC 573.57043f
#define CXC 325.2611f
#define CYC 242.04899f

// z-bucket grid (partition only -> correctness never depends on ZMIN/ZMAX)
#define NB 128
#define ZMIN 0.1f
#define ZMAX 2.1f
#define WB ((ZMAX - ZMIN) / NB)       // 0.015625
#define INVWB (NB / (ZMAX - ZMIN))    // 64.0

#define PAD 16                        // sentinel pad per cloud (overscan target)
#define CLOUD_STRIDE (NPTS + PAD)

#define MASK_WGT 1.3989422804014327f  // exp(0)*inv_sqrt_2pi + 1

// chamfer: 600 blocks (300 groups x 2 dirs interleaved), 256 thr = 4 waves.
// All 4 waves hold the same 64 queries; each scans 1/4 of the candidates.
#define CH_BLKS 600

typedef float __attribute__((ext_vector_type(4))) f4;

__device__ __forceinline__ void backproject_pt(int idx, float d,
                                               float& px, float& py, float& pz) {
    int y = idx / WW;
    int x = idx - y * WW;
    px = ((float)x - CXC) * d * (1.0f / FXC);
    py = ((float)y - CYC) * d * (1.0f / FYC);
    pz = d;
}

__device__ __forceinline__ float min3f(float a, float b, float c) {
    float d;
    asm("v_min3_f32 %0, %1, %2, %3" : "=v"(d) : "v"(a), "v"(b), "v"(c));
    return d;
}

__device__ __forceinline__ int zbucket(float z) {
    int b = (int)((z - ZMIN) * INVWB);
    return b < 0 ? 0 : (b > NB - 1 ? NB - 1 : b);
}

__device__ __forceinline__ int wscan_incl(int v, int lane) {
#pragma unroll
    for (int off = 1; off < 64; off <<= 1) {
        int u = __shfl_up(v, off, 64);
        if (lane >= off) v += u;
    }
    return v;
}

// ---------------- kernel 1: single-workgroup prep (validated R11) ----------------
// ctrl: ints[0]=pos_cnt, [1]=neg_cnt, [2]=done; floats[4..7)=cham,pos,neg sums.
__global__ void __launch_bounds__(1024) prep_k(const float* __restrict__ depth_src,
                                               const float* __restrict__ depth_tgt,
                                               f4* __restrict__ sorted,
                                               int* __restrict__ offs_g,
                                               int* __restrict__ ctrl) {
    __shared__ int cnt[2 * NB];
    __shared__ int cur[2 * NB];
    const int tid = threadIdx.x;

    if (tid < 2 * NB) cnt[tid] = 0;
    if (tid < 8) ctrl[tid] = 0;                 // acci + accf (0 bits == 0.0f)
    if (tid < 2 * PAD) {                        // sentinels for overscan
        int c = tid >> 4, k = tid & (PAD - 1);
        f4 s = {0.0f, 0.0f, 0.0f, 1e30f};
        sorted[c * CLOUD_STRIDE + NPTS + k] = s;
    }
    __syncthreads();

    // P1: histogram
    for (int i = tid; i < 2 * NPTS; i += 1024) {
        int dir = (i >= NPTS);
        int idx = i - dir * NPTS;
        float d = dir ? depth_tgt[idx] : depth_src[idx];
        float px, py, pz;
        backproject_pt(idx, d, px, py, pz);
        atomicAdd(&cnt[dir * NB + zbucket(pz)], 1);
    }
    __syncthreads();

    // P2: exclusive scan, wave c handles cloud c
    if (tid < 128) {
        int c = tid >> 6, lane = tid & 63;
        int v0 = cnt[c * NB + lane];
        int v1 = cnt[c * NB + 64 + lane];
        int s0 = wscan_incl(v0, lane);
        int T0 = __shfl(s0, 63, 64);
        int s1 = wscan_incl(v1, lane) + T0;
        int e0 = s0 - v0, e1 = s1 - v1;
        cur[c * NB + lane] = e0;
        cur[c * NB + 64 + lane] = e1;
        offs_g[c * (NB + 1) + lane] = e0;
        offs_g[c * (NB + 1) + 64 + lane] = e1;
        if (lane == 63) offs_g[c * (NB + 1) + NB] = s1;   // = NPTS
    }
    __syncthreads();

    // P3: scatter into z-bucketed order
    for (int i = tid; i < 2 * NPTS; i += 1024) {
        int dir = (i >= NPTS);
        int idx = i - dir * NPTS;
        float d = dir ? depth_tgt[idx] : depth_src[idx];
        float px, py, pz;
        backproject_pt(idx, d, px, py, pz);
        f4 v = {px, py, pz, fmaf(px, px, fmaf(py, py, pz * pz))};
        int pos = atomicAdd(&cur[dir * NB + zbucket(pz)], 1);
        sorted[dir * CLOUD_STRIDE + pos] = v;
    }
}

// ---------------- kernel 2: 4-wave-cooperative pruned chamfer + mask ----------------
__global__ void __launch_bounds__(256) chamfer_k(const f4* __restrict__ sorted,
                                                 const int* __restrict__ offs,
                                                 const float* __restrict__ pred_PM,
                                                 const float* __restrict__ pred_Ms,
                                                 int* __restrict__ ctrl,
                                                 float* __restrict__ out) {
    const int tid = threadIdx.x;
    const int lane = tid & 63;
    const int w = tid >> 6;                    // wave 0..3
    const int blk = blockIdx.x;
    int* acci = ctrl;                           // [0]=pos_cnt [1]=neg_cnt [2]=done
    float* accf = (float*)(ctrl + 4);

    __shared__ float sm[4][64];

    // ---- mask loss: blocks 0..74, one element per thread ----
    if (blk < 75) {
        int i = blk * 256 + tid;
        float p = fminf(fmaxf(pred_PM[i], 1e-7f), 1.0f - 1e-7f);
        float t = pred_Ms[i];
        float ps = 0.0f, ns = 0.0f;
        int pc = 0, nc = 0;
        if (t > 0.0f)       { ps = -t * logf(p) * MASK_WGT; pc = 1; }
        else if (t == 0.0f) { ns = -logf(1.0f - p) * MASK_WGT; nc = 1; }
#pragma unroll
        for (int off = 32; off; off >>= 1) {
            ps += __shfl_xor(ps, off, 64);
            ns += __shfl_xor(ns, off, 64);
            pc += __shfl_xor(pc, off, 64);
            nc += __shfl_xor(nc, off, 64);
        }
        if (lane == 0) {
            atomicAdd(&accf[1], ps);
            atomicAdd(&accf[2], ns);
            atomicAdd(&acci[0], pc);
            atomicAdd(&acci[1], nc);
        }
    }

    // ---- chamfer: block owns 64 queries; 4 waves split the candidates ----
    const int dir = blk & 1;
    const int grp = blk >> 1;
    const f4* SQ = sorted + dir * CLOUD_STRIDE;
    const f4* SB = sorted + (1 - dir) * CLOUD_STRIDE;
    const int* offB = offs + (1 - dir) * (NB + 1);

    f4 a = SQ[grp * 64 + lane];
    const float n2x = -2.0f * a.x, n2y = -2.0f * a.y, n2z = -2.0f * a.z;
    const float az = a.z, a2 = a.w;
    float mnA = INFINITY, mnB = INFINITY;      // per-wave partial min chains

    int bl = zbucket(az), bh = bl;
#pragma unroll
    for (int off = 32; off; off >>= 1) {
        bl = min(bl, __shfl_xor(bl, off, 64));
        bh = max(bh, __shfl_xor(bh, off, 64));
    }

    // wave w scans 16-candidate batches c0+16w, c0+16w+64, ... (disjoint quarters)
    auto scan_my = [&](int c0, int c1) {
        for (int j = c0 + w * 16; j < c1; j += 64) {
            f4 q[16];
#pragma unroll
            for (int k = 0; k < 16; ++k) q[k] = SB[j + k];
#pragma unroll
            for (int k = 0; k < 16; k += 4) {
                float r0 = fmaf(n2x, q[k+0].x, fmaf(n2y, q[k+0].y, fmaf(n2z, q[k+0].z, q[k+0].w)));
                float r1 = fmaf(n2x, q[k+1].x, fmaf(n2y, q[k+1].y, fmaf(n2z, q[k+1].z, q[k+1].w)));
                float r2 = fmaf(n2x, q[k+2].x, fmaf(n2y, q[k+2].y, fmaf(n2z, q[k+2].z, q[k+2].w)));
                float r3 = fmaf(n2x, q[k+3].x, fmaf(n2y, q[k+3].y, fmaf(n2z, q[k+3].z, q[k+3].w)));
                mnA = min3f(mnA, r0, r1);
                mnB = min3f(mnB, r2, r3);
            }
        }
    };

    scan_my(offB[bl], offB[bh + 1]);

    int lo = bl, hi = bh;
    float m;
    while (true) {
        sm[w][lane] = fminf(mnA, mnB);
        __syncthreads();
        m = fminf(fminf(sm[0][lane], sm[1][lane]),
                  fminf(sm[2][lane], sm[3][lane]));
        float dcur = fmaxf(a2 + m, 0.0f);
        float dl = az - (ZMIN + lo * WB);          // >= 0
        float dr = (ZMIN + (hi + 1) * WB) - az;    // >= 0
        // identical per-lane data in all waves -> block-uniform decisions
        bool anyL = (lo > 0) && __any(dl * dl < dcur);
        bool anyR = (hi < NB - 1) && __any(dr * dr < dcur);
        __syncthreads();                           // reads done before rewrite
        if (!anyL && !anyR) break;
        if (anyL) { --lo; scan_my(offB[lo], offB[lo + 1]); }
        if (anyR) { ++hi; scan_my(offB[hi], offB[hi + 1]); }
    }

    if (w == 0) {
        float v = fmaxf(a2 + m, 0.0f);
#pragma unroll
        for (int off = 32; off; off >>= 1) v += __shfl_xor(v, off, 64);
        if (lane == 0) atomicAdd(&accf[0], v);
    }

    // ---- last-finished-block epilogue ----
    __syncthreads();
    if (tid == 0) {
        __threadfence();
        int old = __hip_atomic_fetch_add(&acci[2], 1, __ATOMIC_ACQ_REL,
                                         __HIP_MEMORY_SCOPE_AGENT);
        if (old == CH_BLKS - 1) {
            __threadfence();
            float cham = __hip_atomic_load(&accf[0], __ATOMIC_RELAXED, __HIP_MEMORY_SCOPE_AGENT);
            float pos  = __hip_atomic_load(&accf[1], __ATOMIC_RELAXED, __HIP_MEMORY_SCOPE_AGENT);
            float neg  = __hip_atomic_load(&accf[2], __ATOMIC_RELAXED, __HIP_MEMORY_SCOPE_AGENT);
            int cp = __hip_atomic_load(&acci[0], __ATOMIC_RELAXED, __HIP_MEMORY_SCOPE_AGENT);
            int cn = __hip_atomic_load(&acci[1], __ATOMIC_RELAXED, __HIP_MEMORY_SCOPE_AGENT);
            out[0] = cham * (1.0f / (float)NPTS);
            float loss = 0.0f;
            if (cp > 0) loss += pos / (float)cp;
            if (cn > 0) loss += neg / (float)cn;
            out[1] = loss;
        }
    }
}

// ---------------- launcher ----------------
extern "C" void kernel_launch(void* const* d_in, const int* in_sizes, int n_in,
                              void* d_out, int out_size, void* d_ws, size_t ws_size,
                              hipStream_t stream) {
    const float* pred_PM   = (const float*)d_in[0];
    const float* pred_Ms   = (const float*)d_in[1];
    const float* depth_src = (const float*)d_in[2];
    const float* depth_tgt = (const float*)d_in[3];
    float* out = (float*)d_out;

    // workspace: ctrl[16 ints] | offs[2*(NB+1)] | (align 16) sorted
    int* ctrl  = (int*)d_ws;
    int* offs  = ctrl + 16;                              // 258 ints
    f4* sorted = (f4*)((char*)d_ws + 2048);              // 2*(NPTS+PAD)*16 B

    prep_k<<<1, 1024, 0, stream>>>(depth_src, depth_tgt, sorted, offs, ctrl);
    chamfer_k<<<CH_BLKS, 256, 0, stream>>>(sorted, offs, pred_PM, pred_Ms,
                                           ctrl, out);
}